// Round 1
// baseline (1929.418 us; speedup 1.0000x reference)
//
#include <hip/hip_runtime.h>
#include <cstdint>
#include <cstddef>

#define BATCH 8192
#define KC 8
#define NC 1024
#define DC 256

// ---------------------------------------------------------------------------
// Kernel A: exact (fp64) squared norms of all codebook entries.
// One wave per entry; block = 256 threads = 4 waves = 4 entries.
// ---------------------------------------------------------------------------
__global__ __launch_bounds__(256) void ee_kernel(const float* __restrict__ entries,
                                                 double* __restrict__ ee) {
    int wave = threadIdx.x >> 6;
    int lane = threadIdx.x & 63;
    int e = blockIdx.x * 4 + wave;          // 0 .. 8191  (k*NC + n)
    const float* ep = entries + (size_t)e * DC;
    float4 v = *(const float4*)(ep + lane * 4);
    double s = (double)v.x * v.x + (double)v.y * v.y +
               (double)v.z * v.z + (double)v.w * v.w;
    #pragma unroll
    for (int off = 32; off > 0; off >>= 1)
        s += __shfl_down(s, off, 64);
    if (lane == 0) ee[e] = s;
}

// ---------------------------------------------------------------------------
// Kernel B: main VQ kernel.
// Grid: (128 b-tiles, 8 k). Block: 256 threads.
// Block handles 64 rows (b0..b0+63) for one k against all 1024 entries.
// Thread t: row r = t&63, n-slice g = t>>6 covering n in [g*256, g*256+256).
// 4-entry register blocking; fp32 32-elem chunks accumulated into fp64.
// ---------------------------------------------------------------------------
__global__ __launch_bounds__(256) void vq_kernel(const float* __restrict__ x,
                                                 const float* __restrict__ entries,
                                                 const double* __restrict__ ee,
                                                 float* __restrict__ out_q,
                                                 float* __restrict__ out_idx,
                                                 double* __restrict__ loss_acc) {
    __shared__ float xs[DC * 65];     // xs[d*65 + r]  (pad 65 -> 2-way banks, free)
    __shared__ double red_d[64 * 4];
    __shared__ int    red_i[64 * 4];
    __shared__ int    idx_row[64];

    const int t  = threadIdx.x;
    const int k  = blockIdx.y;
    const int b0 = blockIdx.x * 64;

    // ---- stage x tile into LDS, transposed: xs[d][r], d = t ----
    const float* xbase = x + ((size_t)b0 * KC + k) * DC;
    #pragma unroll 4
    for (int r = 0; r < 64; ++r) {
        xs[t * 65 + r] = xbase[(size_t)r * KC * DC + t];
    }
    __syncthreads();

    const int g = t >> 6;
    const int r = t & 63;
    const float*  ebase = entries + ((size_t)k * NC + (size_t)g * 256) * DC;
    const double* eek   = ee + (size_t)k * NC + (size_t)g * 256;

    double best = 1.0e300;
    int bestn = 0;

    for (int jj = 0; jj < 64; ++jj) {
        const float4* e4_0 = (const float4*)(ebase + (size_t)(jj * 4 + 0) * DC);
        const float4* e4_1 = (const float4*)(ebase + (size_t)(jj * 4 + 1) * DC);
        const float4* e4_2 = (const float4*)(ebase + (size_t)(jj * 4 + 2) * DC);
        const float4* e4_3 = (const float4*)(ebase + (size_t)(jj * 4 + 3) * DC);

        double dot0 = 0.0, dot1 = 0.0, dot2 = 0.0, dot3 = 0.0;
        for (int d0 = 0; d0 < DC; d0 += 32) {
            float c0 = 0.f, c1 = 0.f, c2 = 0.f, c3 = 0.f;
            #pragma unroll
            for (int d = d0; d < d0 + 32; d += 4) {
                float x0 = xs[(d + 0) * 65 + r];
                float x1 = xs[(d + 1) * 65 + r];
                float x2 = xs[(d + 2) * 65 + r];
                float x3 = xs[(d + 3) * 65 + r];
                float4 ev0 = e4_0[d >> 2];
                float4 ev1 = e4_1[d >> 2];
                float4 ev2 = e4_2[d >> 2];
                float4 ev3 = e4_3[d >> 2];
                c0 = fmaf(x0, ev0.x, c0); c0 = fmaf(x1, ev0.y, c0);
                c0 = fmaf(x2, ev0.z, c0); c0 = fmaf(x3, ev0.w, c0);
                c1 = fmaf(x0, ev1.x, c1); c1 = fmaf(x1, ev1.y, c1);
                c1 = fmaf(x2, ev1.z, c1); c1 = fmaf(x3, ev1.w, c1);
                c2 = fmaf(x0, ev2.x, c2); c2 = fmaf(x1, ev2.y, c2);
                c2 = fmaf(x2, ev2.z, c2); c2 = fmaf(x3, ev2.w, c2);
                c3 = fmaf(x0, ev3.x, c3); c3 = fmaf(x1, ev3.y, c3);
                c3 = fmaf(x2, ev3.z, c3); c3 = fmaf(x3, ev3.w, c3);
            }
            dot0 += (double)c0; dot1 += (double)c1;
            dot2 += (double)c2; dot3 += (double)c3;
        }

        const int n0 = g * 256 + jj * 4;
        double d2_0 = eek[jj * 4 + 0] - 2.0 * dot0;
        double d2_1 = eek[jj * 4 + 1] - 2.0 * dot1;
        double d2_2 = eek[jj * 4 + 2] - 2.0 * dot2;
        double d2_3 = eek[jj * 4 + 3] - 2.0 * dot3;
        // strict < keeps the FIRST (lowest-n) minimum, matching jnp.argmin
        if (d2_0 < best) { best = d2_0; bestn = n0 + 0; }
        if (d2_1 < best) { best = d2_1; bestn = n0 + 1; }
        if (d2_2 < best) { best = d2_2; bestn = n0 + 2; }
        if (d2_3 < best) { best = d2_3; bestn = n0 + 3; }
    }

    red_d[r * 4 + g] = best;
    red_i[r * 4 + g] = bestn;
    __syncthreads();

    if (t < 64) {
        double b = red_d[t * 4];
        int bi = red_i[t * 4];
        #pragma unroll
        for (int g2 = 1; g2 < 4; ++g2) {
            double v = red_d[t * 4 + g2];
            if (v < b) { b = v; bi = red_i[t * 4 + g2]; }   // slices in ascending n
        }
        idx_row[t] = bi;
        out_idx[(size_t)(b0 + t) * KC + k] = (float)bi;

        // xx for the loss (fp64)
        double xx = 0.0;
        for (int d = 0; d < DC; ++d) {
            float xv = xs[d * 65 + t];
            xx += (double)xv * xv;
        }
        double d2min = xx + b;
        #pragma unroll
        for (int off = 32; off > 0; off >>= 1)
            d2min += __shfl_down(d2min, off, 64);
        if (t == 0) atomicAdd(loss_acc, d2min * (1.0 / 65536.0));
    }
    __syncthreads();

    // ---- gather quantized rows to out_q, coalesced over d = t ----
    for (int rr = 0; rr < 64; ++rr) {
        int n = idx_row[rr];
        out_q[((size_t)(b0 + rr) * KC + k) * DC + t] =
            entries[((size_t)k * NC + n) * DC + t];
    }
}

// ---------------------------------------------------------------------------
// Kernel C: finalize loss scalars.
// ---------------------------------------------------------------------------
__global__ void finalize_kernel(const double* __restrict__ loss_acc,
                                float* __restrict__ out) {
    double L = *loss_acc;
    out[(size_t)BATCH * KC * DC + BATCH * KC + 0] = (float)L;
    out[(size_t)BATCH * KC * DC + BATCH * KC + 1] = (float)(0.25 * L);
}

extern "C" void kernel_launch(void* const* d_in, const int* in_sizes, int n_in,
                              void* d_out, int out_size, void* d_ws, size_t ws_size,
                              hipStream_t stream) {
    const float* x       = (const float*)d_in[0];   // [8192, 8, 256]
    const float* entries = (const float*)d_in[1];   // [8, 1024, 256]
    float* out = (float*)d_out;

    double* ee       = (double*)d_ws;                                   // 8*1024 doubles
    double* loss_acc = (double*)((char*)d_ws + (size_t)KC * NC * sizeof(double));

    hipMemsetAsync(loss_acc, 0, sizeof(double), stream);
    ee_kernel<<<KC * NC / 4, 256, 0, stream>>>(entries, ee);

    float* out_q   = out;                                 // 16,777,216 floats
    float* out_idx = out + (size_t)BATCH * KC * DC;       // 65,536 floats

    vq_kernel<<<dim3(BATCH / 64, KC), 256, 0, stream>>>(x, entries, ee, out_q,
                                                        out_idx, loss_acc);
    finalize_kernel<<<1, 1, 0, stream>>>(loss_acc, out);
}

// Round 2
// 457.500 us; speedup vs baseline: 4.2173x; 4.2173x over previous
//
#include <hip/hip_runtime.h>
#include <cstdint>
#include <cstddef>

#define BATCH 8192
#define KC 8
#define NC 1024
#define DC 256
#define TAU 0.02f

typedef __attribute__((ext_vector_type(8))) _Float16 half8;
typedef __attribute__((ext_vector_type(4))) _Float16 half4;
typedef __attribute__((ext_vector_type(4))) float floatx4;

// padded LDS row addressing: 8 rows of 128B packed, +16B pad per group
__device__ __forceinline__ int lrow(int r) { return (r >> 3) * 520 + (r & 7) * 64; } // in halfs

__device__ __forceinline__ void async_load16(const void* g, void* l) {
    __builtin_amdgcn_global_load_lds((const __attribute__((address_space(1))) uint32_t*)g,
                                     (__attribute__((address_space(3))) uint32_t*)l, 16, 0, 0);
}

__device__ __forceinline__ unsigned sortable(float v) {
    unsigned u = __float_as_uint(v);
    return u ^ (unsigned)(((int)u >> 31) | 0x80000000);
}
__device__ __forceinline__ float unsortable(unsigned ks) {
    unsigned u = (ks & 0x80000000u) ? (ks ^ 0x80000000u) : ~ks;
    return __uint_as_float(u);
}
__device__ __forceinline__ unsigned long long umin64(unsigned long long a, unsigned long long b) { return a < b ? a : b; }
__device__ __forceinline__ unsigned long long umax64(unsigned long long a, unsigned long long b) { return a > b ? a : b; }

// ---------------------------------------------------------------------------
// P1: exact fp64 row norms of x. wave per row.
// ---------------------------------------------------------------------------
__global__ __launch_bounds__(256) void xx_kernel(const float* __restrict__ x,
                                                 double* __restrict__ xx64) {
    int wave = threadIdx.x >> 6, lane = threadIdx.x & 63;
    int rid = blockIdx.x * 4 + wave;            // [0, 65536)
    float4 v = ((const float4*)(x + (size_t)rid * DC))[lane];
    double s = (double)v.x * v.x + (double)v.y * v.y + (double)v.z * v.z + (double)v.w * v.w;
    #pragma unroll
    for (int off = 32; off > 0; off >>= 1) s += __shfl_down(s, off, 64);
    if (lane == 0) xx64[rid] = s;
}

// ---------------------------------------------------------------------------
// P2: convert entries -> Ecat f16 [row][768] = [eh | eh | el]; eef = fp32(|e|^2 via fp64)
// ---------------------------------------------------------------------------
__global__ __launch_bounds__(256) void prep_e_kernel(const float* __restrict__ entries,
                                                     _Float16* __restrict__ Ecat,
                                                     float* __restrict__ eef) {
    int wave = threadIdx.x >> 6, lane = threadIdx.x & 63;
    int row = blockIdx.x * 4 + wave;            // [0, 8192) = k*NC + n
    float4 v = ((const float4*)(entries + (size_t)row * DC))[lane];
    half4 h, l;
    h.x = (_Float16)v.x; h.y = (_Float16)v.y; h.z = (_Float16)v.z; h.w = (_Float16)v.w;
    l.x = (_Float16)(v.x - (float)h.x); l.y = (_Float16)(v.y - (float)h.y);
    l.z = (_Float16)(v.z - (float)h.z); l.w = (_Float16)(v.w - (float)h.w);
    _Float16* rp = Ecat + (size_t)row * 768;
    *(half4*)(rp + lane * 4)       = h;
    *(half4*)(rp + 256 + lane * 4) = h;
    *(half4*)(rp + 512 + lane * 4) = l;
    double s = (double)v.x * v.x + (double)v.y * v.y + (double)v.z * v.z + (double)v.w * v.w;
    #pragma unroll
    for (int off = 32; off > 0; off >>= 1) s += __shfl_down(s, off, 64);
    if (lane == 0) eef[row] = (float)s;
}

// ---------------------------------------------------------------------------
// GEMM: per (btile 128, ntile 128, k): S = X*E^T via split-f16 3-pass MFMA.
// 4 waves, each 32 rows x 128 cols. Epilogue: per-row top-2 packed keys -> pairs ws.
// ---------------------------------------------------------------------------
__global__ __launch_bounds__(256) void vq_gemm(const float* __restrict__ x,
                                               const _Float16* __restrict__ Ecat,
                                               const float* __restrict__ eef,
                                               ulonglong2* __restrict__ pairs) {
    __shared__ alignas(16) _Float16 A_lds[16 * 520];   // 128 rows, padded
    __shared__ alignas(16) _Float16 B_lds[16 * 520];

    const int t = threadIdx.x;
    const int k = blockIdx.y;
    const int bt = blockIdx.x >> 3, nt = blockIdx.x & 7;
    const int b0 = bt * 128, n0 = nt * 128;
    const int w = t >> 6, lane = t & 63;
    const int quad = lane >> 4, col = lane & 15;

    floatx4 acc[2][8] = {};

    const _Float16* EcatBase = Ecat + ((size_t)k * NC + n0) * 768;

    for (int dc = 0; dc < 256; dc += 64) {
        // ---- load fp32 A chunk (128 rows x 64 cols), convert to hi/lo f16 ----
        float4 v[8];
        half4 hi[8], lo[8];
        #pragma unroll
        for (int i = 0; i < 8; ++i) {
            int f = i * 256 + t; int arow = f >> 4; int c4 = f & 15;
            v[i] = *(const float4*)(x + ((size_t)(b0 + arow) * KC + k) * DC + dc + c4 * 4);
        }
        #pragma unroll
        for (int i = 0; i < 8; ++i) {
            hi[i].x = (_Float16)v[i].x; hi[i].y = (_Float16)v[i].y;
            hi[i].z = (_Float16)v[i].z; hi[i].w = (_Float16)v[i].w;
            lo[i].x = (_Float16)(v[i].x - (float)hi[i].x);
            lo[i].y = (_Float16)(v[i].y - (float)hi[i].y);
            lo[i].z = (_Float16)(v[i].z - (float)hi[i].z);
            lo[i].w = (_Float16)(v[i].w - (float)hi[i].w);
        }
        // windows: 0: A=hi, B=eh(dc) ; 1: A=hi(keep), B=el(512+dc) ; 2: A=lo, B=eh(256+dc)
        #pragma unroll
        for (int win = 0; win < 3; ++win) {
            const int poff = (win == 0) ? dc : (win == 1 ? 512 + dc : 256 + dc);
            __syncthreads();
            if (win != 1) {
                const half4* src = (win == 0) ? hi : lo;
                #pragma unroll
                for (int i = 0; i < 8; ++i) {
                    int f = i * 256 + t; int arow = f >> 4; int c4 = f & 15;
                    *(half4*)(A_lds + lrow(arow) + c4 * 4) = src[i];
                }
            }
            // B: async global->LDS, 4 insts/wave, 8 rows (1 KB) each
            #pragma unroll
            for (int j = 0; j < 4; ++j) {
                int r8 = w * 4 + j;                       // row-group of 8
                const char* g = (const char*)EcatBase + (size_t)(r8 * 8 + (lane >> 3)) * 1536
                                + (size_t)poff * 2 + (lane & 7) * 16;
                _Float16* lp = B_lds + r8 * 520;          // wave-uniform base
                async_load16(g, lp);
            }
            __syncthreads();
            // ---- compute: 2 k-steps of 32, 16 MFMA each ----
            #pragma unroll
            for (int kk = 0; kk < 64; kk += 32) {
                half8 a0 = *(const half8*)(A_lds + lrow(w * 32 + col)      + kk + quad * 8);
                half8 a1 = *(const half8*)(A_lds + lrow(w * 32 + 16 + col) + kk + quad * 8);
                #pragma unroll
                for (int ni = 0; ni < 8; ++ni) {
                    half8 b = *(const half8*)(B_lds + lrow(ni * 16 + col) + kk + quad * 8);
                    acc[0][ni] = __builtin_amdgcn_mfma_f32_16x16x32_f16(a0, b, acc[0][ni], 0, 0, 0);
                    acc[1][ni] = __builtin_amdgcn_mfma_f32_16x16x32_f16(a1, b, acc[1][ni], 0, 0, 0);
                }
            }
        }
    }

    // ---- epilogue: per-row top-2 of (eef[n] - 2*S) across this ntile ----
    float ev[8];
    #pragma unroll
    for (int ni = 0; ni < 8; ++ni) ev[ni] = eef[(size_t)k * NC + n0 + ni * 16 + col];

    #pragma unroll
    for (int mi = 0; mi < 2; ++mi) {
        #pragma unroll
        for (int reg = 0; reg < 4; ++reg) {
            unsigned long long a1 = ~0ull, a2 = ~0ull;
            #pragma unroll
            for (int ni = 0; ni < 8; ++ni) {
                float val = ev[ni] - 2.0f * acc[mi][ni][reg];
                unsigned long long key =
                    ((unsigned long long)sortable(val) << 32) | (unsigned)(n0 + ni * 16 + col);
                if (key < a1) { a2 = a1; a1 = key; }
                else if (key < a2) { a2 = key; }
            }
            #pragma unroll
            for (int off = 1; off < 16; off <<= 1) {
                unsigned long long o1 = __shfl_xor(a1, off, 16);
                unsigned long long o2 = __shfl_xor(a2, off, 16);
                unsigned long long n1 = umin64(a1, o1);
                unsigned long long n2 = umin64(umax64(a1, o1), umin64(a2, o2));
                a1 = n1; a2 = n2;
            }
            if (col == 0) {
                int row_local = w * 32 + mi * 16 + quad * 4 + reg;
                size_t rid = (size_t)(b0 + row_local) * KC + k;
                pairs[rid * 8 + nt] = make_ulonglong2(a1, a2);
            }
        }
    }
}

// ---------------------------------------------------------------------------
// R: reduce 8 ntile top-2 pairs per row; flag near-ties; write idx + losses.
// ---------------------------------------------------------------------------
__global__ __launch_bounds__(256) void reduce_kernel(const ulonglong2* __restrict__ pairs,
                                                     const double* __restrict__ xx64,
                                                     float* __restrict__ out_idx,
                                                     double* __restrict__ loss_acc,
                                                     int* __restrict__ flag_list,
                                                     int* __restrict__ flag_cnt) {
    int rid = blockIdx.x * 256 + threadIdx.x;   // [0, 65536)
    unsigned long long a1 = ~0ull, a2 = ~0ull;
    #pragma unroll
    for (int j = 0; j < 8; ++j) {
        ulonglong2 p = pairs[(size_t)rid * 8 + j];
        unsigned long long n1 = umin64(a1, p.x);
        unsigned long long n2 = umin64(umax64(a1, p.x), umin64(a2, p.y));
        a1 = n1; a2 = n2;
    }
    float v1 = unsortable((unsigned)(a1 >> 32));
    float v2 = unsortable((unsigned)(a2 >> 32));
    double contrib = 0.0;
    if (v2 - v1 < TAU) {
        int pos = atomicAdd(flag_cnt, 1);
        flag_list[pos] = rid;
    } else {
        out_idx[rid] = (float)(unsigned)(a1 & 0xFFFFFFFFull);
        contrib = (xx64[rid] + (double)v1) * (1.0 / 65536.0);
    }
    #pragma unroll
    for (int off = 32; off > 0; off >>= 1) contrib += __shfl_down(contrib, off, 64);
    if ((threadIdx.x & 63) == 0) atomicAdd(loss_acc, contrib);
}

// ---------------------------------------------------------------------------
// REF: exact fp64 re-resolution of flagged rows (expected ~100 rows).
// One block per flagged row (grid-stride).
// ---------------------------------------------------------------------------
__global__ __launch_bounds__(256) void refine_kernel(const float* __restrict__ x,
                                                     const float* __restrict__ entries,
                                                     const int* __restrict__ flag_list,
                                                     const int* __restrict__ flag_cnt,
                                                     float* __restrict__ out_idx,
                                                     double* __restrict__ loss_acc) {
    __shared__ float xs[DC];
    __shared__ double bd[256];
    __shared__ int    bi[256];
    const int t = threadIdx.x;
    int cnt = *flag_cnt;
    for (int i = blockIdx.x; i < cnt; i += gridDim.x) {
        int rid = flag_list[i];
        int k = rid & 7;
        __syncthreads();
        xs[t] = x[(size_t)rid * DC + t];
        __syncthreads();
        double best = 1.0e300; int bn = 0;
        for (int e = 0; e < 4; ++e) {
            int n = t * 4 + e;
            const float* ep = entries + ((size_t)k * NC + n) * DC;
            double s = 0.0;
            for (int d = 0; d < DC; ++d) {
                double df = (double)xs[d] - (double)ep[d];
                s += df * df;
            }
            if (s < best) { best = s; bn = n; }
        }
        bd[t] = best; bi[t] = bn;
        __syncthreads();
        for (int s2 = 128; s2 > 0; s2 >>= 1) {
            if (t < s2) {
                if (bd[t + s2] < bd[t] || (bd[t + s2] == bd[t] && bi[t + s2] < bi[t])) {
                    bd[t] = bd[t + s2]; bi[t] = bi[t + s2];
                }
            }
            __syncthreads();
        }
        if (t == 0) {
            out_idx[rid] = (float)bi[0];
            atomicAdd(loss_acc, bd[0] * (1.0 / 65536.0));
        }
    }
}

// ---------------------------------------------------------------------------
// G: gather quantized rows. Block = 4 rows, float4-coalesced.
// ---------------------------------------------------------------------------
__global__ __launch_bounds__(256) void gather_kernel(const float* __restrict__ entries,
                                                     const float* __restrict__ out_idx,
                                                     float* __restrict__ out_q) {
    int t = threadIdx.x;
    int r0 = blockIdx.x * 4 + (t >> 6);
    int lane = t & 63;
    int k = r0 & 7;
    int n = (int)out_idx[r0];
    float4 val = *(const float4*)(entries + ((size_t)k * NC + n) * DC + lane * 4);
    *(float4*)(out_q + (size_t)r0 * DC + lane * 4) = val;
}

__global__ void finalize_kernel(const double* __restrict__ loss_acc, float* __restrict__ out) {
    double L = *loss_acc;
    out[(size_t)BATCH * KC * DC + BATCH * KC + 0] = (float)L;
    out[(size_t)BATCH * KC * DC + BATCH * KC + 1] = (float)(0.25 * L);
}

extern "C" void kernel_launch(void* const* d_in, const int* in_sizes, int n_in,
                              void* d_out, int out_size, void* d_ws, size_t ws_size,
                              hipStream_t stream) {
    const float* x       = (const float*)d_in[0];   // [8192, 8, 256]
    const float* entries = (const float*)d_in[1];   // [8, 1024, 256]
    float* out = (float*)d_out;

    // workspace layout
    char* ws = (char*)d_ws;
    double*     loss_acc  = (double*)ws;                         // 8 B
    int*        flag_cnt  = (int*)(ws + 8);                      // 4 B
    float*      eef       = (float*)(ws + 64);                   // 32 KB
    double*     xx64      = (double*)(ws + 64 + 32768);          // 512 KB
    ulonglong2* pairs     = (ulonglong2*)(ws + 64 + 32768 + 524288);          // 8 MB
    int*        flag_list = (int*)(ws + 64 + 32768 + 524288 + 8388608);       // 256 KB
    _Float16*   Ecat      = (_Float16*)(ws + 64 + 32768 + 524288 + 8388608 + 262144); // 12 MB

    float* out_q   = out;                                 // 16,777,216 floats
    float* out_idx = out + (size_t)BATCH * KC * DC;       // 65,536 floats

    hipMemsetAsync(d_ws, 0, 64, stream);
    xx_kernel<<<BATCH * KC / 4, 256, 0, stream>>>(x, xx64);
    prep_e_kernel<<<KC * NC / 4, 256, 0, stream>>>(entries, Ecat, eef);
    vq_gemm<<<dim3(512, 8), 256, 0, stream>>>(x, Ecat, eef, pairs);
    reduce_kernel<<<BATCH * KC / 256, 256, 0, stream>>>(pairs, xx64, out_idx, loss_acc,
                                                        flag_list, flag_cnt);
    refine_kernel<<<64, 256, 0, stream>>>(x, entries, flag_list, flag_cnt, out_idx, loss_acc);
    gather_kernel<<<BATCH * KC / 4, 256, 0, stream>>>(entries, out_idx, out_q);
    finalize_kernel<<<1, 1, 0, stream>>>(loss_acc, out);
}

// Round 3
// 363.221 us; speedup vs baseline: 5.3120x; 1.2596x over previous
//
#include <hip/hip_runtime.h>
#include <cstdint>
#include <cstddef>

#define BATCH 8192
#define KC 8
#define NC 1024
#define DC 256
#define TAU 0.02f

typedef __attribute__((ext_vector_type(8))) _Float16 half8;
typedef __attribute__((ext_vector_type(4))) _Float16 half4;
typedef __attribute__((ext_vector_type(4))) float floatx4;

__device__ __forceinline__ void async_load16(const void* g, void* l) {
    __builtin_amdgcn_global_load_lds((const __attribute__((address_space(1))) uint32_t*)g,
                                     (__attribute__((address_space(3))) uint32_t*)l, 16, 0, 0);
}
__device__ __forceinline__ unsigned sortable(float v) {
    unsigned u = __float_as_uint(v);
    return u ^ (unsigned)(((int)u >> 31) | 0x80000000);
}
__device__ __forceinline__ float unsortable(unsigned ks) {
    unsigned u = (ks & 0x80000000u) ? (ks ^ 0x80000000u) : ~ks;
    return __uint_as_float(u);
}
__device__ __forceinline__ unsigned long long umin64(unsigned long long a, unsigned long long b) { return a < b ? a : b; }
__device__ __forceinline__ unsigned long long umax64(unsigned long long a, unsigned long long b) { return a > b ? a : b; }

// LDS byte offset inside a 128x64-half tile, XOR swizzle: 16 groups of 8 rows
// (1024 B each); row r, 16-B chunk c stored at slot c ^ (r&7).
__device__ __forceinline__ int lidx(int r, int c) {
    return (r >> 3) * 1024 + (r & 7) * 128 + ((c ^ (r & 7)) * 16);
}
__device__ __forceinline__ half8 ldsr(const char* base, int r, int c) {
    return *(const half8*)(base + lidx(r, c));
}

// ---------------------------------------------------------------------------
// P: entries -> Ecat f16 [row][512] = [eh(256) | el(256)]; eef = fp32(|e|^2 via fp64)
// ---------------------------------------------------------------------------
__global__ __launch_bounds__(256) void prep_e_kernel(const float* __restrict__ entries,
                                                     _Float16* __restrict__ Ecat,
                                                     float* __restrict__ eef) {
    int wave = threadIdx.x >> 6, lane = threadIdx.x & 63;
    int row = blockIdx.x * 4 + wave;            // [0, 8192) = k*NC + n
    float4 v = ((const float4*)(entries + (size_t)row * DC))[lane];
    half4 h, l;
    h.x = (_Float16)v.x; h.y = (_Float16)v.y; h.z = (_Float16)v.z; h.w = (_Float16)v.w;
    l.x = (_Float16)(v.x - (float)h.x); l.y = (_Float16)(v.y - (float)h.y);
    l.z = (_Float16)(v.z - (float)h.z); l.w = (_Float16)(v.w - (float)h.w);
    _Float16* rp = Ecat + (size_t)row * 512;
    *(half4*)(rp + lane * 4)       = h;
    *(half4*)(rp + 256 + lane * 4) = l;
    double s = (double)v.x * v.x + (double)v.y * v.y + (double)v.z * v.z + (double)v.w * v.w;
    #pragma unroll
    for (int off = 32; off > 0; off >>= 1) s += __shfl_down(s, off, 64);
    if (lane == 0) eef[row] = (float)s;
}

// ---------------------------------------------------------------------------
// GEMM: grid (64 btiles, 8 k). Block: 256 thr (4 waves x 32 rows x 128 cols).
// Full N=1024 per block; per K-step stage Axh/Axl/Beh/Bel (16 KB each, XOR
// swizzled) and run 3 split-f16 passes with operand reuse (16 b128 : 48 MFMA).
// Per-lane running top-2 across ntiles; one cross-lane merge at the end.
// ---------------------------------------------------------------------------
__global__ __launch_bounds__(256, 2) void vq_gemm(const float* __restrict__ x,
                                                  const _Float16* __restrict__ Ecat,
                                                  const float* __restrict__ eef,
                                                  float* __restrict__ out_idx,
                                                  int* __restrict__ flag_list,
                                                  int* __restrict__ flag_cnt) {
    __shared__ alignas(16) char Axh[16384];
    __shared__ alignas(16) char Axl[16384];
    __shared__ alignas(16) char Beh[16384];
    __shared__ alignas(16) char Bel[16384];
    __shared__ alignas(16) float eef_lds[NC];

    const int t = threadIdx.x;
    const int k = blockIdx.y;
    const int b0 = blockIdx.x * 128;
    const int w = t >> 6, lane = t & 63;
    const int quad = lane >> 4, col = lane & 15;
    const int rl = lane >> 3;                    // row-in-group for staging
    const int cs = (lane & 7) ^ rl;              // swizzled source chunk

    // stage eef row for this k (read later, never overwritten)
    {
        float4 v = ((const float4*)(eef + (size_t)k * NC))[t];
        *(float4*)(eef_lds + t * 4) = v;
    }

    unsigned long long r1[8], r2[8];
    #pragma unroll
    for (int s = 0; s < 8; ++s) { r1[s] = ~0ull; r2[s] = ~0ull; }

    for (int nt = 0; nt < 8; ++nt) {
        const int n0 = nt * 128;
        floatx4 acc[2][8] = {};

        for (int dcs = 0; dcs < 4; ++dcs) {
            const int dc = dcs * 64;
            __syncthreads();                     // prior compute done; tiles reusable
            // ---- B staging: 32 async 1 KB loads; waves 0,1 -> Beh, 2,3 -> Bel ----
            #pragma unroll
            for (int j = 0; j < 8; ++j) {
                int li = w * 8 + j;
                int tile = li >> 4, grp = li & 15;
                const char* src = (const char*)Ecat
                    + ((size_t)(k * NC + n0 + grp * 8 + rl)) * 1024
                    + tile * 512 + dc * 2 + cs * 16;
                char* dst = (tile ? Bel : Beh) + grp * 1024 + lane * 16;
                async_load16(src, dst);
            }
            // ---- A staging: fp32 load, split to hi/lo f16, swizzled ds_write ----
            #pragma unroll
            for (int i = 0; i < 8; ++i) {
                int f = i * 256 + t; int ar = f >> 4; int c4 = f & 15;
                float4 v = *(const float4*)(x + ((size_t)(b0 + ar) * KC + k) * DC + dc + c4 * 4);
                half4 h, l;
                h.x = (_Float16)v.x; h.y = (_Float16)v.y;
                h.z = (_Float16)v.z; h.w = (_Float16)v.w;
                l.x = (_Float16)(v.x - (float)h.x); l.y = (_Float16)(v.y - (float)h.y);
                l.z = (_Float16)(v.z - (float)h.z); l.w = (_Float16)(v.w - (float)h.w);
                int off = (ar >> 3) * 1024 + (ar & 7) * 128
                        + (((c4 >> 1) ^ (ar & 7)) * 16) + (c4 & 1) * 8;
                *(half4*)(Axh + off) = h;
                *(half4*)(Axl + off) = l;
            }
            __syncthreads();                     // staging drained (vmcnt before barrier)
            // ---- compute: 2 x K=32 steps, 48 MFMA each, operand reuse ----
            #pragma unroll
            for (int kk = 0; kk < 2; ++kk) {
                const int cb = kk * 4 + quad;
                half8 ah0 = ldsr(Axh, w * 32 + col, cb);
                half8 ah1 = ldsr(Axh, w * 32 + 16 + col, cb);
                half8 bh[8];
                #pragma unroll
                for (int ni = 0; ni < 8; ++ni) bh[ni] = ldsr(Beh, ni * 16 + col, cb);
                #pragma unroll
                for (int ni = 0; ni < 8; ++ni) {
                    acc[0][ni] = __builtin_amdgcn_mfma_f32_16x16x32_f16(ah0, bh[ni], acc[0][ni], 0, 0, 0);
                    acc[1][ni] = __builtin_amdgcn_mfma_f32_16x16x32_f16(ah1, bh[ni], acc[1][ni], 0, 0, 0);
                }
                #pragma unroll
                for (int ni = 0; ni < 8; ++ni) {    // xh * el (bl transient)
                    half8 bl = ldsr(Bel, ni * 16 + col, cb);
                    acc[0][ni] = __builtin_amdgcn_mfma_f32_16x16x32_f16(ah0, bl, acc[0][ni], 0, 0, 0);
                    acc[1][ni] = __builtin_amdgcn_mfma_f32_16x16x32_f16(ah1, bl, acc[1][ni], 0, 0, 0);
                }
                half8 al0 = ldsr(Axl, w * 32 + col, cb);
                half8 al1 = ldsr(Axl, w * 32 + 16 + col, cb);
                #pragma unroll
                for (int ni = 0; ni < 8; ++ni) {    // xl * eh (bh reused)
                    acc[0][ni] = __builtin_amdgcn_mfma_f32_16x16x32_f16(al0, bh[ni], acc[0][ni], 0, 0, 0);
                    acc[1][ni] = __builtin_amdgcn_mfma_f32_16x16x32_f16(al1, bh[ni], acc[1][ni], 0, 0, 0);
                }
            }
        }
        // ---- epilogue: insert this ntile's candidates into per-lane top-2 ----
        float ev[8];
        #pragma unroll
        for (int ni = 0; ni < 8; ++ni) ev[ni] = eef_lds[n0 + ni * 16 + col];
        #pragma unroll
        for (int mi = 0; mi < 2; ++mi) {
            #pragma unroll
            for (int reg = 0; reg < 4; ++reg) {
                const int s = mi * 4 + reg;
                #pragma unroll
                for (int ni = 0; ni < 8; ++ni) {
                    float val = fmaf(-2.0f, acc[mi][ni][reg], ev[ni]);
                    unsigned long long key = (((unsigned long long)sortable(val)) << 32)
                                           | (unsigned)(n0 + ni * 16 + col);
                    bool lt1 = key < r1[s];
                    bool lt2 = key < r2[s];
                    r2[s] = lt1 ? r1[s] : (lt2 ? key : r2[s]);
                    r1[s] = lt1 ? key : r1[s];
                }
            }
        }
    }

    // ---- final cross-lane (16 cols) top-2 merge; write idx or flag ----
    #pragma unroll
    for (int s = 0; s < 8; ++s) {
        unsigned long long a1 = r1[s], a2 = r2[s];
        #pragma unroll
        for (int off = 1; off < 16; off <<= 1) {
            unsigned long long o1 = __shfl_xor(a1, off, 16);
            unsigned long long o2 = __shfl_xor(a2, off, 16);
            unsigned long long n1 = umin64(a1, o1);
            unsigned long long n2 = umin64(umax64(a1, o1), umin64(a2, o2));
            a1 = n1; a2 = n2;
        }
        if (col == 0) {
            int row_local = w * 32 + (s >> 2) * 16 + quad * 4 + (s & 3);
            int rid = (b0 + row_local) * KC + k;
            float v1 = unsortable((unsigned)(a1 >> 32));
            float v2 = unsortable((unsigned)(a2 >> 32));
            if (v2 - v1 < TAU) {
                int pos = atomicAdd(flag_cnt, 1);
                flag_list[pos] = rid;
            } else {
                out_idx[rid] = (float)(unsigned)(a1 & 0xFFFFFFFFull);
            }
        }
    }
}

// ---------------------------------------------------------------------------
// REF: exact fp64 re-resolution of flagged rows (expected ~100 rows).
// ---------------------------------------------------------------------------
__global__ __launch_bounds__(256) void refine_kernel(const float* __restrict__ x,
                                                     const float* __restrict__ entries,
                                                     const int* __restrict__ flag_list,
                                                     const int* __restrict__ flag_cnt,
                                                     float* __restrict__ out_idx) {
    __shared__ float xs[DC];
    __shared__ double bd[256];
    __shared__ int    bi[256];
    const int t = threadIdx.x;
    int cnt = *flag_cnt;
    for (int i = blockIdx.x; i < cnt; i += gridDim.x) {
        int rid = flag_list[i];
        int k = rid & 7;
        __syncthreads();
        xs[t] = x[(size_t)rid * DC + t];
        __syncthreads();
        double best = 1.0e300; int bn = 0;
        for (int e = 0; e < 4; ++e) {
            int n = t * 4 + e;
            const float* ep = entries + ((size_t)k * NC + n) * DC;
            double s = 0.0;
            for (int d = 0; d < DC; ++d) {
                double df = (double)xs[d] - (double)ep[d];
                s += df * df;
            }
            if (s < best) { best = s; bn = n; }
        }
        bd[t] = best; bi[t] = bn;
        __syncthreads();
        for (int s2 = 128; s2 > 0; s2 >>= 1) {
            if (t < s2) {
                if (bd[t + s2] < bd[t] || (bd[t + s2] == bd[t] && bi[t + s2] < bi[t])) {
                    bd[t] = bd[t + s2]; bi[t] = bi[t + s2];
                }
            }
            __syncthreads();
        }
        if (t == 0) out_idx[rid] = (float)bi[0];
    }
}

// ---------------------------------------------------------------------------
// G: gather quantized rows + exact fp64 loss partials (16 rows per block).
// ---------------------------------------------------------------------------
__global__ __launch_bounds__(256) void gather_loss_kernel(const float* __restrict__ x,
                                                          const float* __restrict__ entries,
                                                          const float* __restrict__ out_idx,
                                                          float* __restrict__ out_q,
                                                          double* __restrict__ partial) {
    __shared__ double red[256];
    const int t = threadIdx.x;
    int rid = blockIdx.x * 16 + (t >> 4);
    int c = t & 15;
    int k = rid & 7;
    int n = (int)out_idx[rid];
    const float4* xp = (const float4*)(x + (size_t)rid * DC);
    const float4* ep = (const float4*)(entries + ((size_t)k * NC + n) * DC);
    float4* op = (float4*)(out_q + (size_t)rid * DC);
    double s = 0.0;
    #pragma unroll
    for (int j = 0; j < 4; ++j) {
        int ci = j * 16 + c;
        float4 xv = xp[ci], evv = ep[ci];
        op[ci] = evv;
        double dx0 = (double)xv.x - (double)evv.x;
        double dx1 = (double)xv.y - (double)evv.y;
        double dx2 = (double)xv.z - (double)evv.z;
        double dx3 = (double)xv.w - (double)evv.w;
        s += dx0 * dx0 + dx1 * dx1 + dx2 * dx2 + dx3 * dx3;
    }
    red[t] = s;
    __syncthreads();
    for (int off = 128; off > 0; off >>= 1) {
        if (t < off) red[t] += red[t + off];
        __syncthreads();
    }
    if (t == 0) partial[blockIdx.x] = red[0];
}

__global__ __launch_bounds__(256) void finalize_kernel(const double* __restrict__ partial,
                                                       float* __restrict__ out) {
    __shared__ double red[256];
    const int t = threadIdx.x;
    double s = 0.0;
    for (int i = t; i < 4096; i += 256) s += partial[i];
    red[t] = s;
    __syncthreads();
    for (int off = 128; off > 0; off >>= 1) {
        if (t < off) red[t] += red[t + off];
        __syncthreads();
    }
    if (t == 0) {
        double L = red[0] * (1.0 / 65536.0);
        out[(size_t)BATCH * KC * DC + BATCH * KC + 0] = (float)L;
        out[(size_t)BATCH * KC * DC + BATCH * KC + 1] = (float)(0.25 * L);
    }
}

extern "C" void kernel_launch(void* const* d_in, const int* in_sizes, int n_in,
                              void* d_out, int out_size, void* d_ws, size_t ws_size,
                              hipStream_t stream) {
    const float* x       = (const float*)d_in[0];   // [8192, 8, 256]
    const float* entries = (const float*)d_in[1];   // [8, 1024, 256]
    float* out = (float*)d_out;

    char* ws = (char*)d_ws;
    int*      flag_cnt  = (int*)ws;                         // [0, 4)
    double*   partial   = (double*)(ws + 4096);             // 32 KB
    float*    eef       = (float*)(ws + 65536);             // 32 KB
    int*      flag_list = (int*)(ws + 131072);              // 256 KB
    _Float16* Ecat      = (_Float16*)(ws + 1048576);        // 8 MB

    float* out_q   = out;                                   // 16,777,216 floats
    float* out_idx = out + (size_t)BATCH * KC * DC;         // 65,536 floats

    hipMemsetAsync(flag_cnt, 0, 4, stream);
    prep_e_kernel<<<KC * NC / 4, 256, 0, stream>>>(entries, Ecat, eef);
    vq_gemm<<<dim3(64, 8), 256, 0, stream>>>(x, Ecat, eef, out_idx, flag_list, flag_cnt);
    refine_kernel<<<64, 256, 0, stream>>>(x, entries, flag_list, flag_cnt, out_idx);
    gather_loss_kernel<<<BATCH * KC / 16, 256, 0, stream>>>(x, entries, out_idx, out_q, partial);
    finalize_kernel<<<1, 256, 0, stream>>>(partial, out);
}

// Round 4
// 271.745 us; speedup vs baseline: 7.1001x; 1.3366x over previous
//
#include <hip/hip_runtime.h>
#include <cstdint>
#include <cstddef>

#define BATCH 8192
#define KC 8
#define NC 1024
#define DC 256
#define TAU 1e-3f

typedef __attribute__((ext_vector_type(8))) _Float16 half8;
typedef __attribute__((ext_vector_type(4))) _Float16 half4;
typedef __attribute__((ext_vector_type(4))) float floatx4;

__device__ __forceinline__ void async_load16(const void* g, void* l) {
    __builtin_amdgcn_global_load_lds((const __attribute__((address_space(1))) uint32_t*)g,
                                     (__attribute__((address_space(3))) uint32_t*)l, 16, 0, 0);
}
__device__ __forceinline__ unsigned sortable(float v) {
    unsigned u = __float_as_uint(v);
    return u ^ (unsigned)(((int)u >> 31) | 0x80000000);
}
__device__ __forceinline__ float unsortable(unsigned ks) {
    unsigned u = (ks & 0x80000000u) ? (ks ^ 0x80000000u) : ~ks;
    return __uint_as_float(u);
}
__device__ __forceinline__ unsigned long long umin64(unsigned long long a, unsigned long long b) { return a < b ? a : b; }
__device__ __forceinline__ unsigned long long umax64(unsigned long long a, unsigned long long b) { return a > b ? a : b; }

// XOR-swizzled LDS tile (128 rows x 64 halfs): row r, 16B chunk c at slot c^(r&7)
__device__ __forceinline__ int lidx(int r, int c) {
    return (r >> 3) * 1024 + (r & 7) * 128 + ((c ^ (r & 7)) * 16);
}
__device__ __forceinline__ half8 ldsr(const char* base, int r, int c) {
    return *(const half8*)(base + lidx(r, c));
}

// ---------------------------------------------------------------------------
// P: entries -> Ecat f16 [row][512] = [eh(256) | el(256)]; eef = fp32(|e|^2 via fp64)
// ---------------------------------------------------------------------------
__global__ __launch_bounds__(256) void prep_e_kernel(const float* __restrict__ entries,
                                                     _Float16* __restrict__ Ecat,
                                                     float* __restrict__ eef) {
    int wave = threadIdx.x >> 6, lane = threadIdx.x & 63;
    int row = blockIdx.x * 4 + wave;            // [0, 8192) = k*NC + n
    float4 v = ((const float4*)(entries + (size_t)row * DC))[lane];
    half4 h, l;
    h.x = (_Float16)v.x; h.y = (_Float16)v.y; h.z = (_Float16)v.z; h.w = (_Float16)v.w;
    l.x = (_Float16)(v.x - (float)h.x); l.y = (_Float16)(v.y - (float)h.y);
    l.z = (_Float16)(v.z - (float)h.z); l.w = (_Float16)(v.w - (float)h.w);
    _Float16* rp = Ecat + (size_t)row * 512;
    *(half4*)(rp + lane * 4)       = h;
    *(half4*)(rp + 256 + lane * 4) = l;
    double s = (double)v.x * v.x + (double)v.y * v.y + (double)v.z * v.z + (double)v.w * v.w;
    #pragma unroll
    for (int off = 32; off > 0; off >>= 1) s += __shfl_down(s, off, 64);
    if (lane == 0) eef[row] = (float)s;
}

// ---------------------------------------------------------------------------
// GEMM: grid 512 (k = blk&7 -> XCD-pinned, bt = blk>>3). 4 waves x 32 rows.
// A (x tile) full-K in registers as split-f16; B double-buffered via
// global_load_lds; 3 passes (xh*eh + xl*eh + xh*el) with bh reuse.
// Fused epilogue: per-row top-2, gap-flag, out_q gather + exact fp64 loss.
// ---------------------------------------------------------------------------
__global__ __launch_bounds__(256, 2) void vq_gemm(const float* __restrict__ x,
                                                  const float* __restrict__ entries,
                                                  const _Float16* __restrict__ Ecat,
                                                  const float* __restrict__ eef,
                                                  float* __restrict__ out_idx,
                                                  float* __restrict__ out_q,
                                                  double* __restrict__ partial,
                                                  int* __restrict__ flag_list,
                                                  int* __restrict__ flag_cnt) {
    __shared__ alignas(16) char Bh[2][16384];
    __shared__ alignas(16) char Bl[2][16384];
    __shared__ float eef_lds[NC];
    __shared__ unsigned long long top2a[128], top2b[128];
    __shared__ int idx_lds[128];
    __shared__ double red[256];

    const int t = threadIdx.x;
    const int k  = blockIdx.x & 7;
    const int b0 = (blockIdx.x >> 3) * 128;
    const int w = t >> 6, lane = t & 63;
    const int quad = lane >> 4, col = lane & 15;
    const int rl = lane >> 3;
    const int cs = (lane & 7) ^ rl;

    { float4 v = ((const float4*)(eef + (size_t)k * NC))[t]; *(float4*)(eef_lds + t * 4) = v; }
    if (t < 128) { top2a[t] = ~0ull; top2b[t] = ~0ull; }

    // ---- A fragments: full K=256 in registers, split f16 hi/lo ----
    half8 Ah[2][8], Al[2][8];
    #pragma unroll
    for (int mi = 0; mi < 2; ++mi) {
        const float* xrow = x + ((size_t)(b0 + w * 32 + mi * 16 + col) * KC + k) * DC + quad * 8;
        #pragma unroll
        for (int ks = 0; ks < 8; ++ks) {
            float4 u0 = *(const float4*)(xrow + ks * 32);
            float4 u1 = *(const float4*)(xrow + ks * 32 + 4);
            float f[8] = {u0.x, u0.y, u0.z, u0.w, u1.x, u1.y, u1.z, u1.w};
            half8 h, l;
            #pragma unroll
            for (int j = 0; j < 8; ++j) {
                h[j] = (_Float16)f[j];
                l[j] = (_Float16)(f[j] - (float)h[j]);
            }
            Ah[mi][ks] = h; Al[mi][ks] = l;
        }
    }

    const char* EcatK = (const char*)(Ecat + (size_t)k * NC * 512);
    #define ISSUE_B(buf, n0b, dcb)                                                          \
        {                                                                                   \
            _Pragma("unroll")                                                               \
            for (int j = 0; j < 8; ++j) {                                                   \
                int li = w * 8 + j; int tile = li >> 4, grp = li & 15;                      \
                const char* src = EcatK + (size_t)((n0b) + grp * 8 + rl) * 1024             \
                                + tile * 512 + (dcb) * 2 + cs * 16;                         \
                char* dst = (tile ? Bl[buf] : Bh[buf]) + grp * 1024 + lane * 16;            \
                async_load16(src, dst);                                                     \
            }                                                                               \
        }

    ISSUE_B(0, 0, 0);

    for (int nt = 0; nt < 8; ++nt) {
        const int n0 = nt * 128;
        floatx4 acc[2][8] = {};
        #pragma unroll
        for (int dcs = 0; dcs < 4; ++dcs) {
            const int step = nt * 4 + dcs;
            __syncthreads();                       // drains loads for buf[cur]
            if (step < 31) {
                const int ns = step + 1;
                ISSUE_B(ns & 1, (ns >> 2) * 128, (ns & 3) * 64);
            }
            const int cur = step & 1;
            #pragma unroll
            for (int kk = 0; kk < 2; ++kk) {
                const int cb = kk * 4 + quad;
                const int ks = dcs * 2 + kk;
                #pragma unroll
                for (int ni = 0; ni < 8; ++ni) {
                    half8 bh = ldsr(Bh[cur], ni * 16 + col, cb);
                    acc[0][ni] = __builtin_amdgcn_mfma_f32_16x16x32_f16(Ah[0][ks], bh, acc[0][ni], 0, 0, 0);
                    acc[1][ni] = __builtin_amdgcn_mfma_f32_16x16x32_f16(Ah[1][ks], bh, acc[1][ni], 0, 0, 0);
                    acc[0][ni] = __builtin_amdgcn_mfma_f32_16x16x32_f16(Al[0][ks], bh, acc[0][ni], 0, 0, 0);
                    acc[1][ni] = __builtin_amdgcn_mfma_f32_16x16x32_f16(Al[1][ks], bh, acc[1][ni], 0, 0, 0);
                    half8 bl = ldsr(Bl[cur], ni * 16 + col, cb);
                    acc[0][ni] = __builtin_amdgcn_mfma_f32_16x16x32_f16(Ah[0][ks], bl, acc[0][ni], 0, 0, 0);
                    acc[1][ni] = __builtin_amdgcn_mfma_f32_16x16x32_f16(Ah[1][ks], bl, acc[1][ni], 0, 0, 0);
                }
            }
        }
        // ---- per-nt epilogue: fold into per-row running top-2 (LDS) ----
        float ev[8];
        #pragma unroll
        for (int ni = 0; ni < 8; ++ni) ev[ni] = eef_lds[n0 + ni * 16 + col];
        #pragma unroll
        for (int mi = 0; mi < 2; ++mi) {
            #pragma unroll
            for (int reg = 0; reg < 4; ++reg) {
                unsigned long long a1 = ~0ull, a2 = ~0ull;
                #pragma unroll
                for (int ni = 0; ni < 8; ++ni) {
                    float val = fmaf(-2.0f, acc[mi][ni][reg], ev[ni]);
                    unsigned long long key = (((unsigned long long)sortable(val)) << 32)
                                           | (unsigned)(n0 + ni * 16 + col);
                    bool lt1 = key < a1, lt2 = key < a2;
                    a2 = lt1 ? a1 : (lt2 ? key : a2);
                    a1 = lt1 ? key : a1;
                }
                #pragma unroll
                for (int off = 1; off < 16; off <<= 1) {
                    unsigned long long o1 = __shfl_xor(a1, off, 16);
                    unsigned long long o2 = __shfl_xor(a2, off, 16);
                    unsigned long long m1 = umin64(a1, o1);
                    unsigned long long m2 = umin64(umax64(a1, o1), umin64(a2, o2));
                    a1 = m1; a2 = m2;
                }
                if (col == 0) {                     // same lane owns this row every nt
                    int row = w * 32 + mi * 16 + quad * 4 + reg;
                    unsigned long long t1 = top2a[row], t2 = top2b[row];
                    top2a[row] = umin64(t1, a1);
                    top2b[row] = umin64(umax64(t1, a1), umin64(t2, a2));
                }
            }
        }
    }

    // ---- final: resolve idx / flag near-ties ----
    __syncthreads();
    if (t < 128) {
        unsigned long long a1 = top2a[t], a2 = top2b[t];
        float v1 = unsortable((unsigned)(a1 >> 32));
        float v2 = unsortable((unsigned)(a2 >> 32));
        int rid = (b0 + t) * KC + k;
        if (v2 - v1 < TAU) {
            int pos = atomicAdd(flag_cnt, 1);
            flag_list[pos] = rid;
            idx_lds[t] = -1;
        } else {
            int n = (int)(unsigned)(a1 & 0xFFFFFFFFull);
            idx_lds[t] = n;
            out_idx[rid] = (float)n;
        }
    }
    __syncthreads();

    // ---- fused gather (out_q) + exact fp64 loss for resolved rows ----
    double s = 0.0;
    #pragma unroll
    for (int rr = 0; rr < 8; ++rr) {
        int r = rr * 16 + (t >> 4);
        int c = t & 15;
        int n = idx_lds[r];
        if (n >= 0) {
            const float4* xp = (const float4*)(x + ((size_t)(b0 + r) * KC + k) * DC);
            const float4* ep = (const float4*)(entries + ((size_t)k * NC + n) * DC);
            float4* op = (float4*)(out_q + ((size_t)(b0 + r) * KC + k) * DC);
            #pragma unroll
            for (int j = 0; j < 4; ++j) {
                int ci = j * 16 + c;
                float4 xv = xp[ci], evv = ep[ci];
                op[ci] = evv;
                double d0 = (double)xv.x - evv.x, d1 = (double)xv.y - evv.y;
                double d2 = (double)xv.z - evv.z, d3 = (double)xv.w - evv.w;
                s += d0 * d0 + d1 * d1 + d2 * d2 + d3 * d3;
            }
        }
    }
    red[t] = s;
    __syncthreads();
    for (int off2 = 128; off2 > 0; off2 >>= 1) {
        if (t < off2) red[t] += red[t + off2];
        __syncthreads();
    }
    if (t == 0) partial[blockIdx.x] = red[0];
    #undef ISSUE_B
}

// ---------------------------------------------------------------------------
// REF: exact fp64 re-resolution of flagged rows; writes idx, out_q, loss.
// ---------------------------------------------------------------------------
__global__ __launch_bounds__(256) void refine_kernel(const float* __restrict__ x,
                                                     const float* __restrict__ entries,
                                                     const int* __restrict__ flag_list,
                                                     const int* __restrict__ flag_cnt,
                                                     float* __restrict__ out_idx,
                                                     float* __restrict__ out_q,
                                                     double* __restrict__ refAcc) {
    __shared__ float xs[DC];
    __shared__ double bd[256];
    __shared__ int    bi[256];
    __shared__ int    win;
    const int t = threadIdx.x;
    int cnt = *flag_cnt;
    for (int i = blockIdx.x; i < cnt; i += gridDim.x) {
        int rid = flag_list[i];
        int k = rid & 7;
        __syncthreads();
        xs[t] = x[(size_t)rid * DC + t];
        __syncthreads();
        double best = 1.0e300; int bn = 0;
        for (int e = 0; e < 4; ++e) {
            int n = t * 4 + e;
            const float* ep = entries + ((size_t)k * NC + n) * DC;
            double s = 0.0;
            for (int d = 0; d < DC; ++d) {
                double df = (double)xs[d] - (double)ep[d];
                s += df * df;
            }
            if (s < best) { best = s; bn = n; }
        }
        bd[t] = best; bi[t] = bn;
        __syncthreads();
        for (int s2 = 128; s2 > 0; s2 >>= 1) {
            if (t < s2) {
                if (bd[t + s2] < bd[t] || (bd[t + s2] == bd[t] && bi[t + s2] < bi[t])) {
                    bd[t] = bd[t + s2]; bi[t] = bi[t + s2];
                }
            }
            __syncthreads();
        }
        if (t == 0) {
            out_idx[rid] = (float)bi[0];
            win = bi[0];
            atomicAdd(refAcc, bd[0]);
        }
        __syncthreads();
        out_q[(size_t)rid * DC + t] = entries[((size_t)k * NC + win) * DC + t];
    }
}

__global__ __launch_bounds__(256) void finalize_kernel(const double* __restrict__ partial,
                                                       const double* __restrict__ refAcc,
                                                       float* __restrict__ out) {
    __shared__ double red[256];
    const int t = threadIdx.x;
    double s = 0.0;
    for (int i = t; i < 512; i += 256) s += partial[i];
    red[t] = s;
    __syncthreads();
    for (int off = 128; off > 0; off >>= 1) {
        if (t < off) red[t] += red[t + off];
        __syncthreads();
    }
    if (t == 0) {
        double L = (red[0] + *refAcc) * (1.0 / 65536.0);
        out[(size_t)BATCH * KC * DC + BATCH * KC + 0] = (float)L;
        out[(size_t)BATCH * KC * DC + BATCH * KC + 1] = (float)(0.25 * L);
    }
}

extern "C" void kernel_launch(void* const* d_in, const int* in_sizes, int n_in,
                              void* d_out, int out_size, void* d_ws, size_t ws_size,
                              hipStream_t stream) {
    const float* x       = (const float*)d_in[0];   // [8192, 8, 256]
    const float* entries = (const float*)d_in[1];   // [8, 1024, 256]
    float* out = (float*)d_out;

    char* ws = (char*)d_ws;
    int*      flag_cnt  = (int*)ws;                         // +0
    double*   refAcc    = (double*)(ws + 8);                // +8
    double*   partial   = (double*)(ws + 4096);             // 512 doubles
    float*    eef       = (float*)(ws + 65536);             // 32 KB
    int*      flag_list = (int*)(ws + 131072);              // 256 KB
    _Float16* Ecat      = (_Float16*)(ws + 1048576);        // 8 MB

    float* out_q   = out;                                   // 16,777,216 floats
    float* out_idx = out + (size_t)BATCH * KC * DC;         // 65,536 floats

    hipMemsetAsync(ws, 0, 16, stream);
    prep_e_kernel<<<KC * NC / 4, 256, 0, stream>>>(entries, Ecat, eef);
    vq_gemm<<<512, 256, 0, stream>>>(x, entries, Ecat, eef, out_idx, out_q,
                                     partial, flag_list, flag_cnt);
    refine_kernel<<<128, 256, 0, stream>>>(x, entries, flag_list, flag_cnt,
                                           out_idx, out_q, refAcc);
    finalize_kernel<<<1, 256, 0, stream>>>(partial, refAcc, out);
}